// Round 8
// baseline (28.820 us; speedup 1.0000x reference)
//
#include <hip/hip_runtime.h>

#define BATCH 262144
#define NUM_LAYERS 64

typedef float f32x2 __attribute__((ext_vector_type(2)));
typedef float f32x4 __attribute__((ext_vector_type(4)));

// U(phi,theta,omega) = Rz(omega) * Ry(theta) * Rz(phi).
// Propagate pre-omega state u_l = Rz(-omega_l)*t_l:
//   u_l = Ry(theta_l) * Rz(phi_l + omega_{l-1}) * u_{l-1}
// omega batch-independent -> sincos(omega/2) per layer precomputed.
//
// ONE batch element per thread (4096 waves = 4/SIMD for latency hiding).
// Packed-f32 math kept by packing across the two AMPLITUDES:
//   z = (Re u0, Re u1), w = (Im u0, Im u1)
// Rz(psi):  az = cps*z + sps*(w.x,-w.y)      aw = cps*w + sps*(-z.x,z.y)
// Ry(th):   z' = cth*az + sth*(-az.y,az.x)   w' = cth*aw + sth*(-aw.y,aw.x)
// store Rz(om): zt = co*z' + so*(w'.x,-w'.y) [+ wt for MODE1]
template <int MODE>
__global__ __launch_bounds__(256) void squbit_kernel(
    const float* __restrict__ X,       // (BATCH, 2)
    const float* __restrict__ W,       // (NUM_LAYERS, 3)
    const float* __restrict__ Bi,      // (NUM_LAYERS, 3)
    float* __restrict__ out)
{
    __shared__ float4 cA[NUM_LAYERS];   // {0.5*w0, 0.5*b0 + hom_prev, 0.5*w1, 0.5*b1}
    __shared__ float2 cOm[NUM_LAYERS];  // {cos(om/2), sin(om/2)}

    const int t = threadIdx.x;
    if (t < NUM_LAYERS) {
        const float w0 = W[t * 3 + 0], w1 = W[t * 3 + 1], w2 = W[t * 3 + 2];
        const float b0 = Bi[t * 3 + 0], b1 = Bi[t * 3 + 1], b2 = Bi[t * 3 + 2];
        float hom_prev = 0.0f;
        if (t > 0) hom_prev = 0.5f * (W[(t - 1) * 3 + 2] + Bi[(t - 1) * 3 + 2]);
        cA[t] = make_float4(0.5f * w0, fmaf(0.5f, b0, hom_prev), 0.5f * w1, 0.5f * b1);
        const float hom = 0.5f * (w2 + b2);
        float so, co;
        __sincosf(hom, &so, &co);
        cOm[t] = make_float2(co, so);
    }
    __syncthreads();

    const int b = blockIdx.x * 256 + t;          // one batch element
    const float2 x = reinterpret_cast<const float2*>(X)[b];

    // packed pre-omega state: z = (Re u0, Re u1), w = (Im u0, Im u1)
    f32x2 z = {1.0f, 0.0f};
    f32x2 w = {0.0f, 0.0f};

    f32x2* o2 = reinterpret_cast<f32x2*>(out);
    f32x4* o4 = reinterpret_cast<f32x4*>(out);

    #pragma unroll 4
    for (int l = 0; l < NUM_LAYERS; ++l) {
        const float4 c = cA[l];
        const float2 om = cOm[l];

        const float hpsi = fmaf(x.x, c.x, c.y);
        const float hth  = fmaf(x.y, c.z, c.w);

        float sps, cps, sth, cth;
        __sincosf(hpsi, &sps, &cps);
        __sincosf(hth,  &sth, &cth);

        // Rz(psi)
        const f32x2 nyw = {w.x, -w.y};
        const f32x2 nxz = {-z.x, z.y};
        const f32x2 az = z * cps + nyw * sps;
        const f32x2 aw = w * cps + nxz * sps;
        // Ry(th)
        const f32x2 raz = {-az.y, az.x};
        const f32x2 raw = {-aw.y, aw.x};
        z = az * cth + raz * sth;
        w = aw * cth + raw * sth;

        // store-side Rz(omega)
        const f32x2 nyw2 = {w.x, -w.y};
        const f32x2 zt = z * om.x + nyw2 * om.y;   // (Re t0, Re t1)
        if (MODE == 0) {
            o2[l * BATCH + b] = zt;
        } else {
            const f32x2 nxz2 = {-z.x, z.y};
            const f32x2 wt = w * om.x + nxz2 * om.y;  // (Im t0, Im t1)
            f32x4 v; v.x = zt.x; v.y = wt.x; v.z = zt.y; v.w = wt.y;
            o4[l * BATCH + b] = v;
        }
    }
}

extern "C" void kernel_launch(void* const* d_in, const int* in_sizes, int n_in,
                              void* d_out, int out_size, void* d_ws, size_t ws_size,
                              hipStream_t stream) {
    const float* X  = (const float*)d_in[0];
    const float* W  = (const float*)d_in[1];
    const float* Bi = (const float*)d_in[2];
    float* out = (float*)d_out;

    dim3 grid(BATCH / 256), block(256);   // 1 batch elem per thread, 4096 waves

    const long long full_complex_floats = (long long)NUM_LAYERS * BATCH * 4;
    if ((long long)out_size >= full_complex_floats) {
        squbit_kernel<1><<<grid, block, 0, stream>>>(X, W, Bi, out);
    } else {
        squbit_kernel<0><<<grid, block, 0, stream>>>(X, W, Bi, out);
    }
}

// Round 9
// 27.486 us; speedup vs baseline: 1.0485x; 1.0485x over previous
//
#include <hip/hip_runtime.h>

#define BATCH 262144
#define NUM_LAYERS 64
#define CHUNK 4

typedef float f32x2 __attribute__((ext_vector_type(2)));
typedef float f32x4 __attribute__((ext_vector_type(4)));

// sin(2*pi*t) / cos(2*pi*t) via the HW trans ops (inputs in revolutions,
// range-reduced with v_fract as the ISA requires).
__device__ __forceinline__ f32x2 sin2pi(f32x2 a) {
    f32x2 r;
    r.x = __builtin_amdgcn_sinf(__builtin_amdgcn_fractf(a.x));
    r.y = __builtin_amdgcn_sinf(__builtin_amdgcn_fractf(a.y));
    return r;
}
__device__ __forceinline__ f32x2 cos2pi(f32x2 a) {
    f32x2 r;
    r.x = __builtin_amdgcn_cosf(__builtin_amdgcn_fractf(a.x));
    r.y = __builtin_amdgcn_cosf(__builtin_amdgcn_fractf(a.y));
    return r;
}

// U(phi,theta,omega) = Rz(omega) * Ry(theta) * Rz(phi).
// Pre-omega state u_l = Rz(-omega_l)*t_l:
//   u_l = Ry(theta_l) * Rz(phi_l + omega_{l-1}) * u_{l-1}
// Constants pre-scaled to REVOLUTIONS (x 1/2pi) so angles go straight to the
// HW sin/cos. Two batch elements per thread in packed-f32 lanes (v_pk_fma).
// Per 4-layer chunk: phase 1 computes all angles+sincos (state-independent,
// trans pipe runs unserialised); phase 2 runs the packed-fma state chain +
// one 16B store per layer.
template <int MODE>
__global__ __launch_bounds__(256) void squbit_kernel(
    const float* __restrict__ X,       // (BATCH, 2)
    const float* __restrict__ W,       // (NUM_LAYERS, 3)
    const float* __restrict__ Bi,      // (NUM_LAYERS, 3)
    float* __restrict__ out)
{
    __shared__ float4 cA[NUM_LAYERS];   // rev-scaled {.5w0, .5b0+hom_prev, .5w1, .5b1}
    __shared__ float2 cOm[NUM_LAYERS];  // {cos(om/2), sin(om/2)}

    const int t = threadIdx.x;
    if (t < NUM_LAYERS) {
        const float INV2PI = 0.15915494309189535f;
        const float w0 = W[t * 3 + 0], w1 = W[t * 3 + 1], w2 = W[t * 3 + 2];
        const float b0 = Bi[t * 3 + 0], b1 = Bi[t * 3 + 1], b2 = Bi[t * 3 + 2];
        float hom_prev = 0.0f;
        if (t > 0) hom_prev = 0.5f * (W[(t - 1) * 3 + 2] + Bi[(t - 1) * 3 + 2]);
        cA[t] = make_float4(0.5f * w0 * INV2PI,
                            fmaf(0.5f, b0, hom_prev) * INV2PI,
                            0.5f * w1 * INV2PI,
                            0.5f * b1 * INV2PI);
        const float hom = 0.5f * (w2 + b2);
        float so, co;
        __sincosf(hom, &so, &co);
        cOm[t] = make_float2(co, so);
    }
    __syncthreads();

    const int g = blockIdx.x * 256 + t;          // batch elems 2g (A), 2g+1 (B)
    const float4 xx = reinterpret_cast<const float4*>(X)[g];

    const f32x2 x0 = {xx.x, xx.z};   // X[:,0] for A,B
    const f32x2 x1 = {xx.y, xx.w};   // X[:,1] for A,B

    // pre-omega state, lanes = (A,B)
    f32x2 ur0 = {1.0f, 1.0f}, ui0 = {0.0f, 0.0f};
    f32x2 ur1 = {0.0f, 0.0f}, ui1 = {0.0f, 0.0f};

    f32x4* o4 = reinterpret_cast<f32x4*>(out);

    for (int l0 = 0; l0 < NUM_LAYERS; l0 += CHUNK) {
        // ---- phase 1: angles + sincos for CHUNK layers (state-independent) ----
        f32x2 sps[CHUNK], cps[CHUNK], sth[CHUNK], cth[CHUNK];
        float2 omc[CHUNK];
        #pragma unroll
        for (int k = 0; k < CHUNK; ++k) {
            const float4 c = cA[l0 + k];
            omc[k] = cOm[l0 + k];
            const f32x2 hpsi = x0 * c.x + c.y;   // revolutions
            const f32x2 hth  = x1 * c.z + c.w;
            sps[k] = sin2pi(hpsi);
            cps[k] = cos2pi(hpsi);
            sth[k] = sin2pi(hth);
            cth[k] = cos2pi(hth);
        }

        // ---- phase 2: packed state chain + stores ----
        #pragma unroll
        for (int k = 0; k < CHUNK; ++k) {
            const int l = l0 + k;
            // Rz(psi): a0 = u0 * (cps - i*sps); a1 = u1 * (cps + i*sps)
            const f32x2 a0r = ui0 * sps[k] + ur0 * cps[k];
            const f32x2 a0i = ui0 * cps[k] - ur0 * sps[k];
            const f32x2 a1r = ur1 * cps[k] - ui1 * sps[k];
            const f32x2 a1i = ui1 * cps[k] + ur1 * sps[k];
            // Ry(th)
            ur0 = cth[k] * a0r - sth[k] * a1r;
            ui0 = cth[k] * a0i - sth[k] * a1i;
            ur1 = sth[k] * a0r + cth[k] * a1r;
            ui1 = sth[k] * a0i + cth[k] * a1i;

            // store-side Rz(omega): t0 = u0*(co - i so), t1 = u1*(co + i so)
            if (MODE == 0) {
                const f32x2 t0r = ui0 * omc[k].y + ur0 * omc[k].x;
                const f32x2 t1r = ur1 * omc[k].x - ui1 * omc[k].y;
                f32x4 v; v.x = t0r.x; v.y = t1r.x; v.z = t0r.y; v.w = t1r.y;
                o4[l * (BATCH / 2) + g] = v;
            } else {
                const f32x2 t0r = ui0 * omc[k].y + ur0 * omc[k].x;
                const f32x2 t0i = ui0 * omc[k].x - ur0 * omc[k].y;
                const f32x2 t1r = ur1 * omc[k].x - ui1 * omc[k].y;
                const f32x2 t1i = ui1 * omc[k].x + ur1 * omc[k].y;
                f32x4 va; va.x = t0r.x; va.y = t0i.x; va.z = t1r.x; va.w = t1i.x;
                f32x4 vb; vb.x = t0r.y; vb.y = t0i.y; vb.z = t1r.y; vb.w = t1i.y;
                o4[(l * BATCH + 2 * g) + 0] = va;
                o4[(l * BATCH + 2 * g) + 1] = vb;
            }
        }
    }
}

extern "C" void kernel_launch(void* const* d_in, const int* in_sizes, int n_in,
                              void* d_out, int out_size, void* d_ws, size_t ws_size,
                              hipStream_t stream) {
    const float* X  = (const float*)d_in[0];
    const float* W  = (const float*)d_in[1];
    const float* Bi = (const float*)d_in[2];
    float* out = (float*)d_out;

    dim3 grid(BATCH / 512), block(256);   // 2 batch elems per thread

    const long long full_complex_floats = (long long)NUM_LAYERS * BATCH * 4;
    if ((long long)out_size >= full_complex_floats) {
        squbit_kernel<1><<<grid, block, 0, stream>>>(X, W, Bi, out);
    } else {
        squbit_kernel<0><<<grid, block, 0, stream>>>(X, W, Bi, out);
    }
}

// Round 11
// 27.119 us; speedup vs baseline: 1.0627x; 1.0135x over previous
//
#include <hip/hip_runtime.h>

#define BATCH 262144
#define NUM_LAYERS 64

typedef float f32x2 __attribute__((ext_vector_type(2)));
typedef float f32x4 __attribute__((ext_vector_type(4)));

// U(phi,theta,omega) = Rz(omega) * Ry(theta) * Rz(phi).
// Pre-omega state u_l = Rz(-omega_l)*t_l:
//   u_l = Ry(theta_l) * Rz(phi_l + omega_{l-1}) * u_{l-1}
// omega batch-independent -> sincos(omega/2) per layer precomputed; the
// store-side Rz(omega) costs 4 packed fma (real part only in MODE 0).
//
// FOUR batch elements per thread, as two packed pair-sets P (elems 2g,2g+1)
// and Q (elems 2g2,2g2+1), carried in packed-f32 lanes (v_pk_fma path).
// Two unit-stride 16B stores per wave per layer (2 KiB/wave/layer) to double
// the per-wave store-byte rate (Little's-law fix for the ~5 TB/s plateau).
// Grid = 256 blocks = 1 block/CU.
template <int MODE>
__global__ __launch_bounds__(256) void squbit_kernel(
    const float* __restrict__ X,       // (BATCH, 2)
    const float* __restrict__ W,       // (NUM_LAYERS, 3)
    const float* __restrict__ Bi,      // (NUM_LAYERS, 3)
    float* __restrict__ out)
{
    __shared__ float4 cA[NUM_LAYERS];   // {0.5*w0, 0.5*b0 + hom_prev, 0.5*w1, 0.5*b1}
    __shared__ float2 cOm[NUM_LAYERS];  // {cos(om/2), sin(om/2)}

    const int t = threadIdx.x;
    if (t < NUM_LAYERS) {
        const float w0 = W[t * 3 + 0], w1 = W[t * 3 + 1], w2 = W[t * 3 + 2];
        const float b0 = Bi[t * 3 + 0], b1 = Bi[t * 3 + 1], b2 = Bi[t * 3 + 2];
        float hom_prev = 0.0f;
        if (t > 0) hom_prev = 0.5f * (W[(t - 1) * 3 + 2] + Bi[(t - 1) * 3 + 2]);
        cA[t] = make_float4(0.5f * w0, fmaf(0.5f, b0, hom_prev), 0.5f * w1, 0.5f * b1);
        const float hom = 0.5f * (w2 + b2);
        float so, co;
        __sincosf(hom, &so, &co);
        cOm[t] = make_float2(co, so);
    }
    __syncthreads();

    const int g  = blockIdx.x * 512 + t;   // pair-set P: elems 2g, 2g+1
    const int g2 = g + 256;                // pair-set Q: elems 2g2, 2g2+1

    const float4 xxP = reinterpret_cast<const float4*>(X)[g];
    const float4 xxQ = reinterpret_cast<const float4*>(X)[g2];

    const f32x2 Px0 = {xxP.x, xxP.z}, Px1 = {xxP.y, xxP.w};
    const f32x2 Qx0 = {xxQ.x, xxQ.z}, Qx1 = {xxQ.y, xxQ.w};

    // pre-omega states, lanes = (elem even, elem odd) of each pair-set
    f32x2 Pur0 = {1.0f, 1.0f}, Pui0 = {0.0f, 0.0f};
    f32x2 Pur1 = {0.0f, 0.0f}, Pui1 = {0.0f, 0.0f};
    f32x2 Qur0 = {1.0f, 1.0f}, Qui0 = {0.0f, 0.0f};
    f32x2 Qur1 = {0.0f, 0.0f}, Qui1 = {0.0f, 0.0f};

    f32x4* o4 = reinterpret_cast<f32x4*>(out);

    #pragma unroll 2
    for (int l = 0; l < NUM_LAYERS; ++l) {
        const float4 c = cA[l];
        const float2 om = cOm[l];

        const f32x2 PhpsiV = Px0 * c.x + c.y;
        const f32x2 PhthV  = Px1 * c.z + c.w;
        const f32x2 QhpsiV = Qx0 * c.x + c.y;
        const f32x2 QhthV  = Qx1 * c.z + c.w;

        float s0, c0, s1, c1, s2, c2, s3, c3;
        float s4, c4, s5, c5, s6, c6, s7, c7;
        __sincosf(PhpsiV.x, &s0, &c0);
        __sincosf(PhpsiV.y, &s1, &c1);
        __sincosf(PhthV.x,  &s2, &c2);
        __sincosf(PhthV.y,  &s3, &c3);
        __sincosf(QhpsiV.x, &s4, &c4);
        __sincosf(QhpsiV.y, &s5, &c5);
        __sincosf(QhthV.x,  &s6, &c6);
        __sincosf(QhthV.y,  &s7, &c7);
        const f32x2 Psps = {s0, s1}, Pcps = {c0, c1};
        const f32x2 Psth = {s2, s3}, Pcth = {c2, c3};
        const f32x2 Qsps = {s4, s5}, Qcps = {c4, c5};
        const f32x2 Qsth = {s6, s7}, Qcth = {c6, c7};

        // ---- pair-set P ----
        {
            const f32x2 a0r = Pui0 * Psps + Pur0 * Pcps;
            const f32x2 a0i = Pui0 * Pcps - Pur0 * Psps;
            const f32x2 a1r = Pur1 * Pcps - Pui1 * Psps;
            const f32x2 a1i = Pui1 * Pcps + Pur1 * Psps;
            Pur0 = Pcth * a0r - Psth * a1r;
            Pui0 = Pcth * a0i - Psth * a1i;
            Pur1 = Psth * a0r + Pcth * a1r;
            Pui1 = Psth * a0i + Pcth * a1i;
        }
        // ---- pair-set Q ----
        {
            const f32x2 a0r = Qui0 * Qsps + Qur0 * Qcps;
            const f32x2 a0i = Qui0 * Qcps - Qur0 * Qsps;
            const f32x2 a1r = Qur1 * Qcps - Qui1 * Qsps;
            const f32x2 a1i = Qui1 * Qcps + Qur1 * Qsps;
            Qur0 = Qcth * a0r - Qsth * a1r;
            Qui0 = Qcth * a0i - Qsth * a1i;
            Qur1 = Qsth * a0r + Qcth * a1r;
            Qui1 = Qsth * a0i + Qcth * a1i;
        }

        // store-side Rz(omega): t0 = u0*(co - i so), t1 = u1*(co + i so)
        if (MODE == 0) {
            const f32x2 Pt0r = Pui0 * om.y + Pur0 * om.x;
            const f32x2 Pt1r = Pur1 * om.x - Pui1 * om.y;
            const f32x2 Qt0r = Qui0 * om.y + Qur0 * om.x;
            const f32x2 Qt1r = Qur1 * om.x - Qui1 * om.y;
            f32x4 vp; vp.x = Pt0r.x; vp.y = Pt1r.x; vp.z = Pt0r.y; vp.w = Pt1r.y;
            f32x4 vq; vq.x = Qt0r.x; vq.y = Qt1r.x; vq.z = Qt0r.y; vq.w = Qt1r.y;
            o4[l * (BATCH / 2) + g]  = vp;
            o4[l * (BATCH / 2) + g2] = vq;
        } else {
            const f32x2 Pt0r = Pui0 * om.y + Pur0 * om.x;
            const f32x2 Pt0i = Pui0 * om.x - Pur0 * om.y;
            const f32x2 Pt1r = Pur1 * om.x - Pui1 * om.y;
            const f32x2 Pt1i = Pui1 * om.x + Pur1 * om.y;
            const f32x2 Qt0r = Qui0 * om.y + Qur0 * om.x;
            const f32x2 Qt0i = Qui0 * om.x - Qur0 * om.y;
            const f32x2 Qt1r = Qur1 * om.x - Qui1 * om.y;
            const f32x2 Qt1i = Qui1 * om.x + Qur1 * om.y;
            f32x4 va; va.x = Pt0r.x; va.y = Pt0i.x; va.z = Pt1r.x; va.w = Pt1i.x;
            f32x4 vb; vb.x = Pt0r.y; vb.y = Pt0i.y; vb.z = Pt1r.y; vb.w = Pt1i.y;
            f32x4 vc; vc.x = Qt0r.x; vc.y = Qt0i.x; vc.z = Qt1r.x; vc.w = Qt1i.x;
            f32x4 vd; vd.x = Qt0r.y; vd.y = Qt0i.y; vd.z = Qt1r.y; vd.w = Qt1i.y;
            o4[(l * BATCH + 2 * g)  + 0] = va;
            o4[(l * BATCH + 2 * g)  + 1] = vb;
            o4[(l * BATCH + 2 * g2) + 0] = vc;
            o4[(l * BATCH + 2 * g2) + 1] = vd;
        }
    }
}

extern "C" void kernel_launch(void* const* d_in, const int* in_sizes, int n_in,
                              void* d_out, int out_size, void* d_ws, size_t ws_size,
                              hipStream_t stream) {
    const float* X  = (const float*)d_in[0];
    const float* W  = (const float*)d_in[1];
    const float* Bi = (const float*)d_in[2];
    float* out = (float*)d_out;

    dim3 grid(BATCH / 1024), block(256);   // 4 batch elems per thread, 1 block/CU

    const long long full_complex_floats = (long long)NUM_LAYERS * BATCH * 4;
    if ((long long)out_size >= full_complex_floats) {
        squbit_kernel<1><<<grid, block, 0, stream>>>(X, W, Bi, out);
    } else {
        squbit_kernel<0><<<grid, block, 0, stream>>>(X, W, Bi, out);
    }
}